// Round 3
// baseline (22998.912 us; speedup 1.0000x reference)
//
#include <hip/hip_runtime.h>
#include <hip/hip_fp16.h>
#include <math.h>

// ---------------- problem constants ----------------
#define B    64
#define S    512
#define TDEC 500
#define EMB  512
#define ENC  512
#define DEC  1024
#define MEL  80
#define NTOK 10
#define NHEAD 8

// d_out layout (floats): mels [64,500,80] | attns [64,500,512] | stops [64,500]
#define MELS_OFF  0
#define ATTNS_OFF 2560000
#define STOPS_OFF 18944000

// ---------------- ws layout (float offsets), 225.4 MB total ----------------
// P0 [16.78M fl]: preF as half (33.55M h) -> later Hbuf as half (32.77M h)
// P1 [16.78M fl]: preB as half -> later qg fp32 (16.78M) -> later Qd fp32 (16.38M)
#define OFF_P0    0UL
#define OFF_P1    16777216UL
#define OFF_ENC   33554432UL     // [B][S][512] fp32
#define OFF_PBUF  50331648UL     // [9][4096][64]
#define OFF_CVEC  52690944UL     // [4096][64]
#define OFF_HT    52953088UL     // [1024][64]
#define OFF_CT    53018624UL     // [1024][64]
#define OFF_EMT   53084160UL     // [512][64]
#define OFF_KG    53116928UL     // [10][512]
#define OFF_SW    53122048UL     // [64][10]
#define OFF_STYLE 53122688UL     // [64][512]
#define OFF_WMS   53155456UL     // [81][1024]
#define OFF_BMS   53238400UL     // [128]
#define OFF_WHHT  53238528UL     // [2][256][1024]
#define OFF_TMPMS 53762816UL     // [32000][81]
#define WS_FLOATS 56354816UL

__device__ __forceinline__ float sigf(float x) { return 1.f / (1.f + __expf(-x)); }
__device__ __forceinline__ float tanhfast(float x) {
  float a = fabsf(x);
  float t = __expf(-2.f * a);
  float r = (1.f - t) / (1.f + t);
  return copysignf(r, x);
}

// ---------------- generic GEMM: C[M,N] = A@W^T + b1 + b2 ----------------
// A row m: fp32 (optionally gathered via rowidx) or fp16. C: fp32 or fp16.
// W is [N][K] fp32 row-major.
template <bool GATHER, bool A16, bool C16>
__global__ __launch_bounds__(256) void k_gemm(
    const float* __restrict__ Af, const __half* __restrict__ Ah,
    const int* __restrict__ rowidx,
    const float* __restrict__ W, const float* __restrict__ b1,
    const float* __restrict__ b2,
    float* __restrict__ Cf, __half* __restrict__ Ch,
    int M, int N, int K)
{
  __shared__ float At[16][68];
  __shared__ float Wt[16][68];
  const int m0 = blockIdx.y * 64, n0 = blockIdx.x * 64;
  const int tid = threadIdx.x;
  const int nq = tid & 15, mq = tid >> 4;       // micro 4(m) x 4(n)
  const int lr = tid >> 2, lc4 = (tid & 3) * 4; // loader
  float acc[4][4] = {};
  for (int kt = 0; kt < K; kt += 16) {
    float4 av = make_float4(0.f,0.f,0.f,0.f), wv = make_float4(0.f,0.f,0.f,0.f);
    int mg = m0 + lr;
    if (mg < M) {
      if constexpr (A16) {
        const __half2* p2 = (const __half2*)(Ah + (size_t)mg * K + kt + lc4);
        float2 f01 = __half22float2(p2[0]);
        float2 f23 = __half22float2(p2[1]);
        av = make_float4(f01.x, f01.y, f23.x, f23.y);
      } else {
        const float* ar = GATHER ? (Af + (size_t)rowidx[mg] * K) : (Af + (size_t)mg * K);
        av = *(const float4*)(ar + kt + lc4);
      }
    }
    int ng = n0 + lr;
    if (ng < N) wv = *(const float4*)(W + (size_t)ng * K + kt + lc4);
    __syncthreads();
    At[lc4+0][lr] = av.x; At[lc4+1][lr] = av.y; At[lc4+2][lr] = av.z; At[lc4+3][lr] = av.w;
    Wt[lc4+0][lr] = wv.x; Wt[lc4+1][lr] = wv.y; Wt[lc4+2][lr] = wv.z; Wt[lc4+3][lr] = wv.w;
    __syncthreads();
#pragma unroll
    for (int kk = 0; kk < 16; kk++) {
      float4 a = *(const float4*)&At[kk][mq*4];
      float4 w = *(const float4*)&Wt[kk][nq*4];
      acc[0][0] += a.x*w.x; acc[0][1] += a.x*w.y; acc[0][2] += a.x*w.z; acc[0][3] += a.x*w.w;
      acc[1][0] += a.y*w.x; acc[1][1] += a.y*w.y; acc[1][2] += a.y*w.z; acc[1][3] += a.y*w.w;
      acc[2][0] += a.z*w.x; acc[2][1] += a.z*w.y; acc[2][2] += a.z*w.z; acc[2][3] += a.z*w.w;
      acc[3][0] += a.w*w.x; acc[3][1] += a.w*w.y; acc[3][2] += a.w*w.z; acc[3][3] += a.w*w.w;
    }
  }
#pragma unroll
  for (int i = 0; i < 4; i++) {
    int m = m0 + mq*4 + i;
    if (m >= M) continue;
    int n = n0 + nq*4;
    if constexpr (C16) {
#pragma unroll
      for (int j = 0; j < 4; j++) {
        if (n + j < N)
          Ch[(size_t)m*N + n + j] =
              __float2half(acc[i][j] + (b1?b1[n+j]:0.f) + (b2?b2[n+j]:0.f));
      }
    } else {
      // float4 store only when N is a multiple of 4 (16B alignment guaranteed)
      if (((N & 3) == 0) && (n + 3 < N)) {
        float4 o;
        o.x = acc[i][0] + (b1?b1[n+0]:0.f) + (b2?b2[n+0]:0.f);
        o.y = acc[i][1] + (b1?b1[n+1]:0.f) + (b2?b2[n+1]:0.f);
        o.z = acc[i][2] + (b1?b1[n+2]:0.f) + (b2?b2[n+2]:0.f);
        o.w = acc[i][3] + (b1?b1[n+3]:0.f) + (b2?b2[n+3]:0.f);
        *(float4*)(Cf + (size_t)m*N + n) = o;
      } else {
#pragma unroll
        for (int j = 0; j < 4; j++) {
          if (n + j < N)
            Cf[(size_t)m*N + n + j] = acc[i][j] + (b1?b1[n+j]:0.f) + (b2?b2[n+j]:0.f);
        }
      }
    }
  }
}

// ---------------- pack mel_w|stop_w into Wms[81][1024], bms[81] ----------------
__global__ void k_pack(const float* __restrict__ mel_w, const float* __restrict__ mel_b,
                       const float* __restrict__ stop_w, const float* __restrict__ stop_b,
                       float* __restrict__ Wms, float* __restrict__ bms)
{
  int i = blockIdx.x * 256 + threadIdx.x;
  if (i < 81 * 1024) Wms[i] = (i < 80*1024) ? mel_w[i] : stop_w[i - 80*1024];
  if (i < 81) bms[i] = (i < 80) ? mel_b[i] : stop_b[0];
}

__global__ void k_zero(float* __restrict__ p, int n)
{
  int i = blockIdx.x * 256 + threadIdx.x;
  if (i < n) p[i] = 0.f;
}

// ---------------- Whh transpose: WhhT[dir][k][j] = Whh_dir[j][k] ----------------
__global__ __launch_bounds__(256) void k_transpose(
    const float* __restrict__ Whh_f, const float* __restrict__ Whh_b,
    float* __restrict__ WhhT)
{
  const int dir = blockIdx.z;
  const float* src = dir ? Whh_b : Whh_f;
  float* dst = WhhT + (size_t)dir * 262144;
  __shared__ float tile[32][33];
  int j0 = blockIdx.x * 32, k0 = blockIdx.y * 32;
  int tx = threadIdx.x & 31, ty = threadIdx.x >> 5;  // ty 0..7
#pragma unroll
  for (int i = 0; i < 4; i++)
    tile[ty*4+i][tx] = src[(size_t)(j0 + ty*4+i)*256 + k0 + tx];
  __syncthreads();
#pragma unroll
  for (int i = 0; i < 4; i++)
    dst[(size_t)(k0 + ty*4+i)*1024 + j0 + tx] = tile[tx][ty*4+i];
}

// ---------------- encoder bi-LSTM scan ----------------
// 64 blocks = (dir, batch-pair); 1024 threads; thread t = gate-row j.
// Weights streamed from L2 via transposed layout (coalesced); h broadcast via LDS.
__global__ __launch_bounds__(1024) void k_enc_scan(
    const __half* __restrict__ pre_f, const __half* __restrict__ pre_b,
    const float* __restrict__ WhhT, float* __restrict__ enc)
{
  const int bi = blockIdx.x;
  const int dir = bi >> 5, pr = bi & 31;
  const int b0 = pr * 2;
  const __half* pre = dir ? pre_b : pre_f;
  const float* wT = WhhT + (size_t)dir * 262144;
  const int tid = threadIdx.x;
  __shared__ float hs[2][256];
  __shared__ float gbuf[2][1024];
  if (tid < 512) hs[tid >> 8][tid & 255] = 0.f;
  float creg = 0.f;
  __syncthreads();
  for (int step = 0; step < S; step++) {
    int s = dir ? (S - 1 - step) : step;
    float a0 = __half2float(pre[((size_t)(b0+0)*S + s)*1024 + tid]);
    float a1 = __half2float(pre[((size_t)(b0+1)*S + s)*1024 + tid]);
    const float4* h40 = (const float4*)hs[0];
    const float4* h41 = (const float4*)hs[1];
#pragma unroll 4
    for (int k4 = 0; k4 < 64; k4++) {
      float4 h0 = h40[k4], h1 = h41[k4];
      float w0 = wT[(size_t)(k4*4+0)*1024 + tid];
      float w1 = wT[(size_t)(k4*4+1)*1024 + tid];
      float w2 = wT[(size_t)(k4*4+2)*1024 + tid];
      float w3 = wT[(size_t)(k4*4+3)*1024 + tid];
      a0 += w0*h0.x + w1*h0.y + w2*h0.z + w3*h0.w;
      a1 += w0*h1.x + w1*h1.y + w2*h1.z + w3*h1.w;
    }
    gbuf[0][tid] = a0;
    gbuf[1][tid] = a1;
    __syncthreads();
    if (tid < 512) {
      int b = tid >> 8, u = tid & 255;
      float gi = gbuf[b][u], gf = gbuf[b][256+u], gg = gbuf[b][512+u], go = gbuf[b][768+u];
      float c = sigf(gf) * creg + sigf(gi) * tanhfast(gg);
      float h = sigf(go) * tanhfast(c);
      creg = c;
      hs[b][u] = h;
      enc[((size_t)(b0+b)*S + s)*ENC + dir*256 + u] = h;
    }
    __syncthreads();
  }
}

// ---------------- GST attention weights -> sw[64,10] ----------------
__global__ __launch_bounds__(256) void k_gst(
    const float* __restrict__ qg, const float* __restrict__ kg, float* __restrict__ sw)
{
  const int b = blockIdx.x, tid = threadIdx.x;
  __shared__ float kt[10][512];
  __shared__ float red[256];
  for (int i = tid; i < 10*512; i += 256) kt[i >> 9][i & 511] = kg[i];
  float accw[10];
#pragma unroll
  for (int t = 0; t < 10; t++) accw[t] = 0.f;
  __syncthreads();
  for (int s = tid; s < S; s += 256) {
    const float* q = qg + ((size_t)b*S + s) * ENC;
    for (int n = 0; n < NHEAD; n++) {
      float sc[10];
#pragma unroll
      for (int t = 0; t < 10; t++) sc[t] = 0.f;
#pragma unroll 4
      for (int h4 = 0; h4 < 16; h4++) {
        float4 qv = *(const float4*)(q + n*64 + h4*4);
#pragma unroll
        for (int t = 0; t < 10; t++) {
          sc[t] += qv.x*kt[t][n*64+h4*4+0] + qv.y*kt[t][n*64+h4*4+1]
                 + qv.z*kt[t][n*64+h4*4+2] + qv.w*kt[t][n*64+h4*4+3];
        }
      }
      float m = sc[0];
#pragma unroll
      for (int t = 1; t < 10; t++) m = fmaxf(m, sc[t]);
      float e[10]; float den = 0.f;
#pragma unroll
      for (int t = 0; t < 10; t++) { e[t] = __expf((sc[t] - m) * 0.125f); den += e[t]; }
      float inv = 1.f / den;
#pragma unroll
      for (int t = 0; t < 10; t++) accw[t] += e[t] * inv;
    }
  }
  for (int t = 0; t < 10; t++) {
    red[tid] = accw[t];
    __syncthreads();
    for (int off = 128; off > 0; off >>= 1) {
      if (tid < off) red[tid] += red[tid + off];
      __syncthreads();
    }
    if (tid == 0) sw[b*10 + t] = red[0] / (8.f * 512.f);
    __syncthreads();
  }
}

// ---------------- style: style[b,:] = (sw@tokens)@proj_w^T + proj_b ----------------
__global__ __launch_bounds__(256) void k_style(
    const float* __restrict__ sw, const float* __restrict__ tokens,
    const float* __restrict__ proj_w, const float* __restrict__ proj_b,
    float* __restrict__ style)
{
  const int b = blockIdx.x, tid = threadIdx.x;
  __shared__ float sv[512];
  __shared__ float swl[10];
  if (tid < 10) swl[tid] = sw[b*10 + tid];
  __syncthreads();
  for (int e = tid; e < 512; e += 256) {
    float a = 0.f;
#pragma unroll
    for (int t = 0; t < 10; t++) a += swl[t] * tokens[t*512 + e];
    sv[e] = a;
  }
  __syncthreads();
  for (int e = tid; e < 512; e += 256) {
    float a = proj_b[e];
    const float* pr = proj_w + (size_t)e * 512;
#pragma unroll 8
    for (int k4 = 0; k4 < 128; k4++) {
      float4 s4 = *(const float4*)&sv[k4*4];
      float4 p4 = *(const float4*)(pr + k4*4);
      a += s4.x*p4.x + s4.y*p4.y + s4.z*p4.z + s4.w*p4.w;
    }
    style[b*512 + e] = a;
  }
}

// ---------------- enc += style ; emT[e][b] = mean_s enc ----------------
__global__ __launch_bounds__(256) void k_encsm(
    float* __restrict__ enc, const float* __restrict__ style, float* __restrict__ emT)
{
  const int b = blockIdx.x, tid = threadIdx.x;
  __shared__ float st[512];
  for (int e = tid; e < 512; e += 256) st[e] = style[b*512 + e];
  __syncthreads();
  float acc0 = 0.f, acc1 = 0.f;
  for (int s = 0; s < S; s++) {
    float* row = enc + ((size_t)b*S + s) * ENC;
    float v0 = row[tid]       + st[tid];
    float v1 = row[tid + 256] + st[tid + 256];
    row[tid] = v0; row[tid + 256] = v1;
    acc0 += v0; acc1 += v1;
  }
  emT[(size_t)tid*64 + b]        = acc0 * (1.f / 512.f);
  emT[(size_t)(tid+256)*64 + b]  = acc1 * (1.f / 512.f);
}

// ---------------- cvecT[j][b] = dbih[j]+dbhh[j] + sum_k enc_mean[b,k]*dWih[j,80+k] ----
__global__ __launch_bounds__(1024) void k_cvec(
    const float* __restrict__ dWih, const float* __restrict__ dbih,
    const float* __restrict__ dbhh, const float* __restrict__ emT,
    float* __restrict__ cvecT)
{
  const int j = blockIdx.x * 16 + (threadIdx.x >> 6);
  const int b = threadIdx.x & 63;
  const float* wr = dWih + (size_t)j * 592 + 80;
  float a = dbih[j] + dbhh[j];
#pragma unroll 8
  for (int k = 0; k < 512; k++) a += wr[k] * emT[(size_t)k*64 + b];
  cvecT[(size_t)j*64 + b] = a;
}

// ---------------- decoder per-step partial GEMM ----------------
// blocks 0..511: (rb = bi>>3: 64 rows; kc = bi&7: 128 k of hT) -> pbuf[kc]
// blocks 512..543: mel part (80 cols of dWih, teacher-forced prev mel) -> pbuf[8]
__global__ __launch_bounds__(512) void k_dec_main(
    const float* __restrict__ dWhh, const float* __restrict__ dWih,
    const float* __restrict__ hT, const float* __restrict__ mel_target,
    float* __restrict__ pbuf, int t)
{
  __shared__ float sm[16384];  // 64 KB
  const int tid = threadIdx.x;
  const int bi = blockIdx.x;
  if (bi < 512) {
    const int rb = bi >> 3, kc = bi & 7;
    float (*wT)[68] = (float(*)[68])sm;  // [128][68]
#pragma unroll
    for (int i = 0; i < 16; i++) {
      int e = tid + i * 512;
      int rl = e >> 7, kl = e & 127;
      wT[kl][rl] = dWhh[(size_t)(rb*64 + rl)*1024 + kc*128 + kl];
    }
    __syncthreads();
    const int rs = tid >> 5, bh = tid & 31;  // rows rs*4..+3, b = bh*2,+1
    float acc[4][2] = {};
    const float* hp = hT + (size_t)(kc*128)*64 + bh*2;
#pragma unroll 8
    for (int k = 0; k < 128; k++) {
      float2 hv = *(const float2*)(hp + (size_t)k*64);
      float4 wv = *(const float4*)&wT[k][rs*4];
      acc[0][0] += wv.x*hv.x; acc[0][1] += wv.x*hv.y;
      acc[1][0] += wv.y*hv.x; acc[1][1] += wv.y*hv.y;
      acc[2][0] += wv.z*hv.x; acc[2][1] += wv.z*hv.y;
      acc[3][0] += wv.w*hv.x; acc[3][1] += wv.w*hv.y;
    }
#pragma unroll
    for (int i = 0; i < 4; i++) {
      int row = rb*64 + rs*4 + i;
      *(float2*)&pbuf[((size_t)kc*4096 + row)*64 + bh*2] = make_float2(acc[i][0], acc[i][1]);
    }
  } else {
    const int mb = bi - 512;                      // 0..31 -> rows mb*128..
    float (*wmT)[132] = (float(*)[132])sm;        // [80][132]
    float* mt = sm + 80*132;                      // [80][66]
#pragma unroll
    for (int i = 0; i < 20; i++) {
      int e = tid + i * 512;
      int rl = e / 80, kl = e % 80;
      wmT[kl][rl] = dWih[(size_t)(mb*128 + rl)*592 + kl];
    }
#pragma unroll
    for (int i = 0; i < 10; i++) {
      int e = tid + i * 512;
      int bb = e / 80, kl = e % 80;
      float v = (t > 0) ? mel_target[((size_t)bb*TDEC + (t-1))*MEL + kl] : 0.f;
      mt[kl*66 + bb] = v;
    }
    __syncthreads();
    const int rs = tid >> 5, bh = tid & 31;  // rows rs*8..+7, b = bh*2,+1
    float acc[8][2] = {};
#pragma unroll 4
    for (int k = 0; k < 80; k++) {
      float2 hv = *(const float2*)&mt[k*66 + bh*2];
      float4 w0 = *(const float4*)&wmT[k][rs*8];
      float4 w1 = *(const float4*)&wmT[k][rs*8 + 4];
      acc[0][0] += w0.x*hv.x; acc[0][1] += w0.x*hv.y;
      acc[1][0] += w0.y*hv.x; acc[1][1] += w0.y*hv.y;
      acc[2][0] += w0.z*hv.x; acc[2][1] += w0.z*hv.y;
      acc[3][0] += w0.w*hv.x; acc[3][1] += w0.w*hv.y;
      acc[4][0] += w1.x*hv.x; acc[4][1] += w1.x*hv.y;
      acc[5][0] += w1.y*hv.x; acc[5][1] += w1.y*hv.y;
      acc[6][0] += w1.z*hv.x; acc[6][1] += w1.z*hv.y;
      acc[7][0] += w1.w*hv.x; acc[7][1] += w1.w*hv.y;
    }
#pragma unroll
    for (int i = 0; i < 8; i++) {
      int row = mb*128 + rs*8 + i;
      *(float2*)&pbuf[((size_t)8*4096 + row)*64 + bh*2] = make_float2(acc[i][0], acc[i][1]);
    }
  }
}

// ---------------- decoder reduce + LSTM cell + h publish ----------------
__global__ __launch_bounds__(1024) void k_dec_reduce(
    const float* __restrict__ pbuf, const float* __restrict__ cvecT,
    float* __restrict__ cT, float* __restrict__ hT, __half* __restrict__ Hbuf, int t)
{
  const int blk = blockIdx.x;     // 64 blocks: u-chunk 16
  const int tid = threadIdx.x;
  const int ul = tid >> 6, b = tid & 63;
  const int u = blk*16 + ul;
  float g[4];
#pragma unroll
  for (int gi = 0; gi < 4; gi++) {
    int row = gi*1024 + u;
    float a = cvecT[(size_t)row*64 + b];
#pragma unroll
    for (int kc = 0; kc < 9; kc++) a += pbuf[((size_t)kc*4096 + row)*64 + b];
    g[gi] = a;
  }
  float c = sigf(g[1]) * cT[(size_t)u*64 + b] + sigf(g[0]) * tanhfast(g[2]);
  float h = sigf(g[3]) * tanhfast(c);
  cT[(size_t)u*64 + b] = c;
  hT[(size_t)u*64 + b] = h;
  __shared__ float ht[16][65];
  ht[ul][b] = h;
  __syncthreads();
  int b2 = tid >> 4, ul2 = tid & 15;
  Hbuf[((size_t)t*64 + b2)*1024 + blk*16 + ul2] = __float2half(ht[ul2][b2]);
}

// ---------------- deferred decoder attention: scores + softmax -> attns ----------------
// 8 t-rows per block; LDS = 37.4 KB
__global__ __launch_bounds__(256) void k_attn(
    const float* __restrict__ Qd, const float* __restrict__ enc, float* __restrict__ attns)
{
  const int ch = blockIdx.x, bb = blockIdx.y;
  const int t0 = ch * 8;
  const int tid = threadIdx.x;
  __shared__ float Qt[8][516];
  __shared__ float sc[8][516];
  __shared__ float et[16][68];
  for (int i = tid; i < 8*512; i += 256) {
    int tr = i >> 9, k = i & 511;
    int tt = t0 + tr;
    Qt[tr][k] = (tt < TDEC) ? Qd[((size_t)tt*64 + bb)*512 + k] : 0.f;
  }
  const int tq = tid >> 5, sq = tid & 31;  // row tq (0..7), s pair sq
  for (int st = 0; st < 8; st++) {
    int s0 = st * 64;
    float a0 = 0.f, a1 = 0.f;
    for (int kt = 0; kt < 512; kt += 16) {
      int sl = tid >> 2, k4 = (tid & 3) * 4;
      float4 ev = *(const float4*)(enc + ((size_t)bb*S + s0 + sl)*ENC + kt + k4);
      __syncthreads();
      et[k4+0][sl] = ev.x; et[k4+1][sl] = ev.y; et[k4+2][sl] = ev.z; et[k4+3][sl] = ev.w;
      __syncthreads();
#pragma unroll
      for (int kk = 0; kk < 16; kk++) {
        float q0 = Qt[tq][kt+kk];
        float2 e2 = *(const float2*)&et[kk][sq*2];
        a0 += q0*e2.x; a1 += q0*e2.y;
      }
    }
    *(float2*)&sc[tq][s0+sq*2] = make_float2(a0, a1);
  }
  __syncthreads();
  int row = tid >> 5, li = tid & 31;
  float m = -1e30f;
  for (int s = li; s < 512; s += 32) m = fmaxf(m, sc[row][s]);
#pragma unroll
  for (int off = 1; off < 32; off <<= 1) m = fmaxf(m, __shfl_xor(m, off, 64));
  float den = 0.f;
  for (int s = li; s < 512; s += 32) {
    float e = __expf(sc[row][s] - m);
    sc[row][s] = e;
    den += e;
  }
#pragma unroll
  for (int off = 1; off < 32; off <<= 1) den += __shfl_xor(den, off, 64);
  float inv = 1.f / den;
  int tt = t0 + row;
  if (tt < TDEC) {
    for (int s = li; s < 512; s += 32)
      attns[((size_t)bb*TDEC + tt)*512 + s] = sc[row][s] * inv;
  }
}

// ---------------- mel/stop epilogue ----------------
__global__ void k_melout(const float* __restrict__ tmp,
                         float* __restrict__ mels, float* __restrict__ stops)
{
  int i = blockIdx.x * 256 + threadIdx.x;
  if (i >= 32000 * 81) return;
  int tb = i / 81, n = i % 81;
  int t = tb >> 6, b = tb & 63;
  float v = tmp[i];
  if (n < 80) mels[((size_t)b*TDEC + t)*MEL + n] = v;
  else        stops[(size_t)b*TDEC + t] = sigf(v);
}

// ---------------- host launcher ----------------
extern "C" void kernel_launch(void* const* d_in, const int* in_sizes, int n_in,
                              void* d_out, int out_size, void* d_ws, size_t ws_size,
                              hipStream_t stream)
{
  (void)in_sizes; (void)n_in; (void)out_size;
  if (ws_size < WS_FLOATS * sizeof(float)) return;  // clean accuracy-fail diagnostic

  const int*   text       = (const int*)  d_in[0];
  const float* mel_target = (const float*)d_in[1];
  const float* emb_table  = (const float*)d_in[3];
  const float* Wih_f = (const float*)d_in[4];
  const float* Whh_f = (const float*)d_in[5];
  const float* bih_f = (const float*)d_in[6];
  const float* bhh_f = (const float*)d_in[7];
  const float* Wih_b = (const float*)d_in[8];
  const float* Whh_b = (const float*)d_in[9];
  const float* bih_b = (const float*)d_in[10];
  const float* bhh_b = (const float*)d_in[11];
  const float* tokens = (const float*)d_in[12];
  const float* q_w = (const float*)d_in[13];
  const float* q_b = (const float*)d_in[14];
  const float* k_w = (const float*)d_in[15];
  const float* k_b = (const float*)d_in[16];
  const float* proj_w = (const float*)d_in[17];
  const float* proj_b = (const float*)d_in[18];
  const float* dWih = (const float*)d_in[19];
  const float* dWhh = (const float*)d_in[20];
  const float* dbih = (const float*)d_in[21];
  const float* dbhh = (const float*)d_in[22];
  const float* attn_w = (const float*)d_in[23];
  const float* attn_b = (const float*)d_in[24];
  const float* mel_w = (const float*)d_in[25];
  const float* mel_b = (const float*)d_in[26];
  const float* stop_w = (const float*)d_in[27];
  const float* stop_b = (const float*)d_in[28];

  float* ws = (float*)d_ws;
  __half* preF  = (__half*)(ws + OFF_P0);   // 33.55M halfs
  __half* preB  = (__half*)(ws + OFF_P1);
  __half* Hbuf  = (__half*)(ws + OFF_P0);   // after scans (preF dead), 32.77M halfs
  float*  qg    = ws + OFF_P1;              // after scans (preB dead)
  float*  Qd    = ws + OFF_P1;              // after k_gst (qg dead)
  float*  enc   = ws + OFF_ENC;
  float*  pbuf  = ws + OFF_PBUF;
  float*  cvecT = ws + OFF_CVEC;
  float*  hT    = ws + OFF_HT;
  float*  cT    = ws + OFF_CT;
  float*  emT   = ws + OFF_EMT;
  float*  kg    = ws + OFF_KG;
  float*  swb   = ws + OFF_SW;
  float*  style = ws + OFF_STYLE;
  float*  Wms   = ws + OFF_WMS;
  float*  bms   = ws + OFF_BMS;
  float*  WhhT  = ws + OFF_WHHT;
  float*  tmpMS = ws + OFF_TMPMS;

  float* out = (float*)d_out;
  float* out_mels  = out + MELS_OFF;
  float* out_attns = out + ATTNS_OFF;
  float* out_stops = out + STOPS_OFF;

  k_pack<<<(81*1024 + 255)/256, 256, 0, stream>>>(mel_w, mel_b, stop_w, stop_b, Wms, bms);
  k_transpose<<<dim3(32, 8, 2), 256, 0, stream>>>(Whh_f, Whh_b, WhhT);

  // encoder input projections (embedding gather fused), fp16 output
  dim3 gpre(1024/64, 32768/64);
  k_gemm<true,false,true><<<gpre, 256, 0, stream>>>(
      emb_table, nullptr, text, Wih_f, bih_f, bhh_f, nullptr, preF, 32768, 1024, 512);
  k_gemm<true,false,true><<<gpre, 256, 0, stream>>>(
      emb_table, nullptr, text, Wih_b, bih_b, bhh_b, nullptr, preB, 32768, 1024, 512);

  // GST keys
  k_gemm<false,false,false><<<dim3(8,1), 256, 0, stream>>>(
      tokens, nullptr, nullptr, k_w, k_b, nullptr, kg, nullptr, 10, 512, 512);

  // encoder scan (both dirs concurrently; weights streamed from L2)
  k_enc_scan<<<64, 1024, 0, stream>>>(preF, preB, WhhT, enc);

  // GST: q = enc@q_w^T + q_b (pre-style enc), then attn weights, style, enc update
  k_gemm<false,false,false><<<dim3(8,512), 256, 0, stream>>>(
      enc, nullptr, nullptr, q_w, q_b, nullptr, qg, nullptr, 32768, 512, 512);
  k_gst<<<64, 256, 0, stream>>>(qg, kg, swb);
  k_style<<<64, 256, 0, stream>>>(swb, tokens, proj_w, proj_b, style);
  k_encsm<<<64, 256, 0, stream>>>(enc, style, emT);

  // decoder constants
  k_cvec<<<256, 1024, 0, stream>>>(dWih, dbih, dbhh, emT, cvecT);
  k_zero<<<512, 256, 0, stream>>>(hT, 131072);  // zeros hT and adjacent cT

  // decoder scan
  for (int t = 0; t < TDEC; t++) {
    k_dec_main<<<544, 512, 0, stream>>>(dWhh, dWih, hT, mel_target, pbuf, t);
    k_dec_reduce<<<64, 1024, 0, stream>>>(pbuf, cvecT, cT, hT, Hbuf, t);
  }

  // deferred outputs (read fp16 Hbuf)
  k_gemm<false,true,false><<<dim3(8,500), 256, 0, stream>>>(
      nullptr, Hbuf, nullptr, attn_w, attn_b, nullptr, Qd, nullptr, 32000, 512, 1024);
  k_gemm<false,true,false><<<dim3(2,500), 256, 0, stream>>>(
      nullptr, Hbuf, nullptr, Wms, bms, nullptr, tmpMS, nullptr, 32000, 81, 1024);
  k_attn<<<dim3(63,64), 256, 0, stream>>>(Qd, enc, out_attns);
  k_melout<<<(32000*81 + 255)/256, 256, 0, stream>>>(tmpMS, out_mels, out_stops);
}

// Round 5
// 10003.880 us; speedup vs baseline: 2.2990x; 2.2990x over previous
//
#include <hip/hip_runtime.h>
#include <hip/hip_fp16.h>
#include <math.h>

// ---------------- problem constants ----------------
#define B    64
#define S    512
#define TDEC 500
#define ENC  512
#define DEC  1024
#define MEL  80
#define NTOK 10
#define NHEAD 8

// d_out layout (floats): mels [64,500,80] | attns [64,500,512] | stops [64,500]
#define MELS_OFF  0
#define ATTNS_OFF 2560000
#define STOPS_OFF 18944000

// ---------------- ws layout (float offsets) ≈ 223.9 MB ----------------
// P0: preF(fp16) -> encFrag(bf16) -> HbufFrag(bf16)
// P1: preB(fp16) -> qg(f32) -> Qd(f32)
// ENC: enc f32; its first 8.39M floats host Aemb(bf16) BEFORE the scan runs
// SCR: WhhT (pre-scan only) -> Adec | melLin (decoder) -> tmpMS (post-decoder)
#define OFF_P0     0UL
#define OFF_P1     16777216UL
#define OFF_ENC    33554432UL
#define OFF_SCR    50331648UL
#define SCR_MEL_SUB 2293760UL
#define OFF_WFF    54525952UL
#define OFF_WFB    54788096UL
#define OFF_QWF    55050240UL
#define OFF_AWF    55181312UL
#define OFF_WMSF   55443456UL
#define OFF_BMS    55508992UL
#define OFF_CVEC   55509120UL
#define OFF_CT     55771264UL
#define OFF_HTB    55836800UL
#define OFF_EMT    55902336UL
#define OFF_KG     55935104UL
#define OFF_SW     55940224UL
#define OFF_STYLE  55940864UL
#define WS_FLOATS  55973632UL

typedef __attribute__((ext_vector_type(8))) short short8;   // 8 bf16 (4 VGPR)
typedef __attribute__((ext_vector_type(4))) float f32x4;    // MFMA acc

__device__ __forceinline__ float sigf(float x) { return 1.f / (1.f + __expf(-x)); }
__device__ __forceinline__ float tanhfast(float x) {
  float a = fabsf(x);
  float t = __expf(-2.f * a);
  float r = (1.f - t) / (1.f + t);
  return copysignf(r, x);
}
__device__ __forceinline__ unsigned short f2bf(float x) {
  union { float f; unsigned u; } v; v.f = x;
  unsigned r = (v.u + 0x7fffu + ((v.u >> 16) & 1u)) >> 16;
  return (unsigned short)r;
}

// ============ fragment packing ============
// Fragment slot convention (same for A and B operands, both stored [out][K]):
//   out-index = tile*16 + (lane&15); k = kstep*32 + ((lane>>4)&3)*8 + i, i=0..7
//   buffer layout: frag[(tile*KS + kstep)*512 + lane*8 + i]  (bf16)

// generic W [N][K] f32 -> frag (zero-pad beyond N,K)
__global__ void k_pack_wfrag(const float* __restrict__ W, unsigned short* __restrict__ out,
                             int Ntiles, int KS, int N, int K)
{
  int idx = blockIdx.x * 256 + threadIdx.x;
  if (idx >= Ntiles * KS * 64) return;
  int l = idx & 63, ks = (idx >> 6) % KS, nt = idx / (64 * KS);
  int n = nt * 16 + (l & 15);
  int kb = ks * 32 + ((l >> 4) & 3) * 8;
  unsigned short v[8];
#pragma unroll
  for (int i = 0; i < 8; i++) {
    int k = kb + i;
    v[i] = (n < N && k < K) ? f2bf(W[(size_t)n * K + k]) : 0;
  }
  *(uint4*)(out + (size_t)idx * 8) = *(uint4*)v;
}

// mel_w[80][1024] | stop_w[1024] | zeros -> [8 nt][32 ks][512]
__global__ void k_pack_wms_frag(const float* __restrict__ mel_w, const float* __restrict__ stop_w,
                                unsigned short* __restrict__ out)
{
  int idx = blockIdx.x * 256 + threadIdx.x;
  if (idx >= 8 * 32 * 64) return;
  int l = idx & 63, ks = (idx >> 6) & 31, nt = idx >> 11;
  int n = nt * 16 + (l & 15);
  int kb = ks * 32 + ((l >> 4) & 3) * 8;
  unsigned short v[8];
#pragma unroll
  for (int i = 0; i < 8; i++) {
    int k = kb + i;
    float x = (n < 80) ? mel_w[(size_t)n * 1024 + k] : (n == 80 ? stop_w[k] : 0.f);
    v[i] = f2bf(x);
  }
  *(uint4*)(out + (size_t)idx * 8) = *(uint4*)v;
}

__global__ void k_pack_bms(const float* __restrict__ mel_b, const float* __restrict__ stop_b,
                           float* __restrict__ bms)
{
  int i = threadIdx.x;
  if (i < 128) bms[i] = (i < 80) ? mel_b[i] : (i == 80 ? stop_b[0] : 0.f);
}

// embeddings gathered: A[m][k] = emb_table[text[m]][k], M=32768,K=512 -> frag
__global__ void k_pack_aemb(const int* __restrict__ text, const float* __restrict__ emb,
                            unsigned short* __restrict__ out)
{
  int idx = blockIdx.x * 256 + threadIdx.x;            // 2048*16*64
  if (idx >= 2048 * 16 * 64) return;
  int l = idx & 63, ks = (idx >> 6) & 15, mt = idx >> 10;
  int m = mt * 16 + (l & 15);
  int kb = ks * 32 + ((l >> 4) & 3) * 8;
  const float* row = emb + (size_t)text[m] * 512 + kb;
  unsigned short v[8];
#pragma unroll
  for (int i = 0; i < 8; i++) v[i] = f2bf(row[i]);
  *(uint4*)(out + (size_t)idx * 8) = *(uint4*)v;
}

// enc f32 [32768][512] -> frag
__global__ void k_pack_enc(const float* __restrict__ enc, unsigned short* __restrict__ out)
{
  int idx = blockIdx.x * 256 + threadIdx.x;
  if (idx >= 2048 * 16 * 64) return;
  int l = idx & 63, ks = (idx >> 6) & 15, mt = idx >> 10;
  int m = mt * 16 + (l & 15);
  int kb = ks * 32 + ((l >> 4) & 3) * 8;
  const float* row = enc + (size_t)m * 512 + kb;
  unsigned short v[8];
#pragma unroll
  for (int i = 0; i < 8; i++) v[i] = f2bf(row[i]);
  *(uint4*)(out + (size_t)idx * 8) = *(uint4*)v;
}

// decoder weights: [256 wg][35 ks][512]; within tile m16: unit=wg*4+(m16>>2), gate=m16&3
// k<1024 -> dWhh[gate*1024+unit][k]; 1024<=k<1104 -> dWih[...][k-1024] (mel cols); else 0
__global__ void k_pack_adec(const float* __restrict__ dWhh, const float* __restrict__ dWih,
                            unsigned short* __restrict__ out)
{
  int idx = blockIdx.x * 256 + threadIdx.x;            // 256*35*64
  if (idx >= 256 * 35 * 64) return;
  int l = idx & 63;
  int ks = (idx >> 6) % 35;
  int wg = idx / (35 * 64);
  int m16 = l & 15;
  int u = wg * 4 + (m16 >> 2);
  int g = (m16 & 3) * 1024 + u;
  int kb = ks * 32 + ((l >> 4) & 3) * 8;
  unsigned short v[8];
#pragma unroll
  for (int i = 0; i < 8; i++) {
    int k = kb + i;
    float x = (k < 1024) ? dWhh[(size_t)g * 1024 + k]
            : (k < 1104) ? dWih[(size_t)g * 592 + (k - 1024)] : 0.f;
    v[i] = f2bf(x);
  }
  *(uint4*)(out + (size_t)idx * 8) = *(uint4*)v;
}

// teacher-forcing mel, bf16 linear [t][b][96]: j<80: mel_target[b][t-1][j] (t>0), else 0
__global__ void k_pack_mel(const float* __restrict__ mel_target, unsigned short* __restrict__ out)
{
  int idx = blockIdx.x * 256 + threadIdx.x;            // 32000*12 uint4 slots
  if (idx >= 32000 * 12) return;
  int row = idx / 12, q = idx % 12;
  int t = row >> 6, b = row & 63;
  unsigned short v[8];
#pragma unroll
  for (int i = 0; i < 8; i++) {
    int j = q * 8 + i;
    float x = (t > 0 && j < 80) ? mel_target[((size_t)b * TDEC + (t - 1)) * MEL + j] : 0.f;
    v[i] = f2bf(x);
  }
  *(uint4*)(out + (size_t)idx * 8) = *(uint4*)v;
}

__global__ void k_zero(float* __restrict__ p, int n)
{
  int i = blockIdx.x * 256 + threadIdx.x;
  if (i < n) p[i] = 0.f;
}

// ============ MFMA GEMM: C[M,N] = A@W^T + b1 + b2 ============
// A frag [Mtiles][KS][512], W frag [Ntiles][KS][512]; WG 256 thr = 4 waves stacked in N.
// wave tile = 64 x (NSUB*16); WG tile = 64 x (4*NSUB*16). M,N exact multiples.
template <int KS, int NSUB, bool C16>
__global__ __launch_bounds__(256) void k_mgemm(
    const unsigned short* __restrict__ Af, const unsigned short* __restrict__ Bf,
    const float* __restrict__ b1, const float* __restrict__ b2,
    float* __restrict__ Cf, __half* __restrict__ Ch, int N)
{
  const int tid = threadIdx.x, l = tid & 63, w = tid >> 6;
  const int mt0 = blockIdx.y * 4;
  const int nt0 = blockIdx.x * 4 * NSUB + w * NSUB;
  const short8* Ap = (const short8*)Af;
  const short8* Bp = (const short8*)Bf;
  f32x4 acc[4][NSUB];
#pragma unroll
  for (int mi = 0; mi < 4; mi++)
#pragma unroll
    for (int ni = 0; ni < NSUB; ni++) acc[mi][ni] = (f32x4){0.f, 0.f, 0.f, 0.f};

#pragma unroll 4
  for (int ks = 0; ks < KS; ks++) {
    short8 a[4], b[NSUB];
#pragma unroll
    for (int mi = 0; mi < 4; mi++) a[mi] = Ap[(size_t)((mt0 + mi) * KS + ks) * 64 + l];
#pragma unroll
    for (int ni = 0; ni < NSUB; ni++) b[ni] = Bp[(size_t)((nt0 + ni) * KS + ks) * 64 + l];
#pragma unroll
    for (int mi = 0; mi < 4; mi++)
#pragma unroll
      for (int ni = 0; ni < NSUB; ni++)
        acc[mi][ni] = __builtin_amdgcn_mfma_f32_16x16x32_bf16(a[mi], b[ni], acc[mi][ni], 0, 0, 0);
  }

#pragma unroll
  for (int mi = 0; mi < 4; mi++) {
#pragma unroll
    for (int ni = 0; ni < NSUB; ni++) {
      int n = (nt0 + ni) * 16 + (l & 15);
      float bias = (b1 ? b1[n] : 0.f) + (b2 ? b2[n] : 0.f);
      int mbase = (mt0 + mi) * 16 + (l >> 4) * 4;
#pragma unroll
      for (int r = 0; r < 4; r++) {
        float v = acc[mi][ni][r] + bias;
        size_t off = (size_t)(mbase + r) * N + n;
        if constexpr (C16) Ch[off] = __float2half(v);
        else               Cf[off] = v;
      }
    }
  }
}

// ============ small fp32 GEMM (GST keys only): C[M,N]=A@W^T + b1 ============
__global__ __launch_bounds__(256) void k_gemm(
    const float* __restrict__ A, const float* __restrict__ W,
    const float* __restrict__ b1, float* __restrict__ C, int M, int N, int K)
{
  __shared__ float At[16][68];
  __shared__ float Wt[16][68];
  const int m0 = blockIdx.y * 64, n0 = blockIdx.x * 64;
  const int tid = threadIdx.x;
  const int nq = tid & 15, mq = tid >> 4;
  const int lr = tid >> 2, lc4 = (tid & 3) * 4;
  float acc[4][4] = {};
  for (int kt = 0; kt < K; kt += 16) {
    float4 av = make_float4(0.f,0.f,0.f,0.f), wv = make_float4(0.f,0.f,0.f,0.f);
    int mg = m0 + lr;
    if (mg < M) av = *(const float4*)(A + (size_t)mg * K + kt + lc4);
    int ng = n0 + lr;
    if (ng < N) wv = *(const float4*)(W + (size_t)ng * K + kt + lc4);
    __syncthreads();
    At[lc4+0][lr] = av.x; At[lc4+1][lr] = av.y; At[lc4+2][lr] = av.z; At[lc4+3][lr] = av.w;
    Wt[lc4+0][lr] = wv.x; Wt[lc4+1][lr] = wv.y; Wt[lc4+2][lr] = wv.z; Wt[lc4+3][lr] = wv.w;
    __syncthreads();
#pragma unroll
    for (int kk = 0; kk < 16; kk++) {
      float4 a = *(const float4*)&At[kk][mq*4];
      float4 w = *(const float4*)&Wt[kk][nq*4];
      acc[0][0] += a.x*w.x; acc[0][1] += a.x*w.y; acc[0][2] += a.x*w.z; acc[0][3] += a.x*w.w;
      acc[1][0] += a.y*w.x; acc[1][1] += a.y*w.y; acc[1][2] += a.y*w.z; acc[1][3] += a.y*w.w;
      acc[2][0] += a.z*w.x; acc[2][1] += a.z*w.y; acc[2][2] += a.z*w.z; acc[2][3] += a.z*w.w;
      acc[3][0] += a.w*w.x; acc[3][1] += a.w*w.y; acc[3][2] += a.w*w.z; acc[3][3] += a.w*w.w;
    }
  }
#pragma unroll
  for (int i = 0; i < 4; i++) {
    int m = m0 + mq*4 + i;
    if (m >= M) continue;
    int n = n0 + nq*4;
#pragma unroll
    for (int j = 0; j < 4; j++)
      if (n + j < N) C[(size_t)m*N + n + j] = acc[i][j] + (b1 ? b1[n+j] : 0.f);
  }
}

// ---------------- Whh transpose ----------------
__global__ __launch_bounds__(256) void k_transpose(
    const float* __restrict__ Whh_f, const float* __restrict__ Whh_b,
    float* __restrict__ WhhT)
{
  const int dir = blockIdx.z;
  const float* src = dir ? Whh_b : Whh_f;
  float* dst = WhhT + (size_t)dir * 262144;
  __shared__ float tile[32][33];
  int j0 = blockIdx.x * 32, k0 = blockIdx.y * 32;
  int tx = threadIdx.x & 31, ty = threadIdx.x >> 5;
#pragma unroll
  for (int i = 0; i < 4; i++)
    tile[ty*4+i][tx] = src[(size_t)(j0 + ty*4+i)*256 + k0 + tx];
  __syncthreads();
#pragma unroll
  for (int i = 0; i < 4; i++)
    dst[(size_t)(k0 + ty*4+i)*1024 + j0 + tx] = tile[tx][ty*4+i];
}

// ---------------- encoder bi-LSTM scan ----------------
__global__ __launch_bounds__(1024) void k_enc_scan(
    const __half* __restrict__ pre_f, const __half* __restrict__ pre_b,
    const float* __restrict__ WhhT, float* __restrict__ enc)
{
  const int bi = blockIdx.x;
  const int dir = bi >> 5, pr = bi & 31;
  const int b0 = pr * 2;
  const __half* pre = dir ? pre_b : pre_f;
  const float* wT = WhhT + (size_t)dir * 262144;
  const int tid = threadIdx.x;
  __shared__ float hs[2][256];
  __shared__ float gbuf[2][1024];
  if (tid < 512) hs[tid >> 8][tid & 255] = 0.f;
  float creg = 0.f;
  __syncthreads();
  for (int step = 0; step < S; step++) {
    int s = dir ? (S - 1 - step) : step;
    float a0 = __half2float(pre[((size_t)(b0+0)*S + s)*1024 + tid]);
    float a1 = __half2float(pre[((size_t)(b0+1)*S + s)*1024 + tid]);
    const float4* h40 = (const float4*)hs[0];
    const float4* h41 = (const float4*)hs[1];
#pragma unroll 4
    for (int k4 = 0; k4 < 64; k4++) {
      float4 h0 = h40[k4], h1 = h41[k4];
      float w0 = wT[(size_t)(k4*4+0)*1024 + tid];
      float w1 = wT[(size_t)(k4*4+1)*1024 + tid];
      float w2 = wT[(size_t)(k4*4+2)*1024 + tid];
      float w3 = wT[(size_t)(k4*4+3)*1024 + tid];
      a0 += w0*h0.x + w1*h0.y + w2*h0.z + w3*h0.w;
      a1 += w0*h1.x + w1*h1.y + w2*h1.z + w3*h1.w;
    }
    gbuf[0][tid] = a0;
    gbuf[1][tid] = a1;
    __syncthreads();
    if (tid < 512) {
      int b = tid >> 8, u = tid & 255;
      float gi = gbuf[b][u], gf = gbuf[b][256+u], gg = gbuf[b][512+u], go = gbuf[b][768+u];
      float c = sigf(gf) * creg + sigf(gi) * tanhfast(gg);
      float h = sigf(go) * tanhfast(c);
      creg = c;
      hs[b][u] = h;
      enc[((size_t)(b0+b)*S + s)*ENC + dir*256 + u] = h;
    }
    __syncthreads();
  }
}

// ---------------- GST attention weights -> sw[64,10] ----------------
__global__ __launch_bounds__(256) void k_gst(
    const float* __restrict__ qg, const float* __restrict__ kg, float* __restrict__ sw)
{
  const int b = blockIdx.x, tid = threadIdx.x;
  __shared__ float kt[10][512];
  __shared__ float red[256];
  for (int i = tid; i < 10*512; i += 256) kt[i >> 9][i & 511] = kg[i];
  float accw[10];
#pragma unroll
  for (int t = 0; t < 10; t++) accw[t] = 0.f;
  __syncthreads();
  for (int s = tid; s < S; s += 256) {
    const float* q = qg + ((size_t)b*S + s) * ENC;
    for (int n = 0; n < NHEAD; n++) {
      float sc[10];
#pragma unroll
      for (int t = 0; t < 10; t++) sc[t] = 0.f;
#pragma unroll 4
      for (int h4 = 0; h4 < 16; h4++) {
        float4 qv = *(const float4*)(q + n*64 + h4*4);
#pragma unroll
        for (int t = 0; t < 10; t++) {
          sc[t] += qv.x*kt[t][n*64+h4*4+0] + qv.y*kt[t][n*64+h4*4+1]
                 + qv.z*kt[t][n*64+h4*4+2] + qv.w*kt[t][n*64+h4*4+3];
        }
      }
      float m = sc[0];
#pragma unroll
      for (int t = 1; t < 10; t++) m = fmaxf(m, sc[t]);
      float e[10]; float den = 0.f;
#pragma unroll
      for (int t = 0; t < 10; t++) { e[t] = __expf((sc[t] - m) * 0.125f); den += e[t]; }
      float inv = 1.f / den;
#pragma unroll
      for (int t = 0; t < 10; t++) accw[t] += e[t] * inv;
    }
  }
  for (int t = 0; t < 10; t++) {
    red[tid] = accw[t];
    __syncthreads();
    for (int off = 128; off > 0; off >>= 1) {
      if (tid < off) red[tid] += red[tid + off];
      __syncthreads();
    }
    if (tid == 0) sw[b*10 + t] = red[0] / (8.f * 512.f);
    __syncthreads();
  }
}

// ---------------- style ----------------
__global__ __launch_bounds__(256) void k_style(
    const float* __restrict__ sw, const float* __restrict__ tokens,
    const float* __restrict__ proj_w, const float* __restrict__ proj_b,
    float* __restrict__ style)
{
  const int b = blockIdx.x, tid = threadIdx.x;
  __shared__ float sv[512];
  __shared__ float swl[10];
  if (tid < 10) swl[tid] = sw[b*10 + tid];
  __syncthreads();
  for (int e = tid; e < 512; e += 256) {
    float a = 0.f;
#pragma unroll
    for (int t = 0; t < 10; t++) a += swl[t] * tokens[t*512 + e];
    sv[e] = a;
  }
  __syncthreads();
  for (int e = tid; e < 512; e += 256) {
    float a = proj_b[e];
    const float* pr = proj_w + (size_t)e * 512;
#pragma unroll 8
    for (int k4 = 0; k4 < 128; k4++) {
      float4 s4 = *(const float4*)&sv[k4*4];
      float4 p4 = *(const float4*)(pr + k4*4);
      a += s4.x*p4.x + s4.y*p4.y + s4.z*p4.z + s4.w*p4.w;
    }
    style[b*512 + e] = a;
  }
}

// ---------------- enc += style ; emT ----------------
__global__ __launch_bounds__(256) void k_encsm(
    float* __restrict__ enc, const float* __restrict__ style, float* __restrict__ emT)
{
  const int b = blockIdx.x, tid = threadIdx.x;
  __shared__ float st[512];
  for (int e = tid; e < 512; e += 256) st[e] = style[b*512 + e];
  __syncthreads();
  float acc0 = 0.f, acc1 = 0.f;
  for (int s = 0; s < S; s++) {
    float* row = enc + ((size_t)b*S + s) * ENC;
    float v0 = row[tid]       + st[tid];
    float v1 = row[tid + 256] + st[tid + 256];
    row[tid] = v0; row[tid + 256] = v1;
    acc0 += v0; acc1 += v1;
  }
  emT[(size_t)tid*64 + b]        = acc0 * (1.f / 512.f);
  emT[(size_t)(tid+256)*64 + b]  = acc1 * (1.f / 512.f);
}

// ---------------- cvecT[g][b] (fp32, exact enc_mean part + biases) ----------------
__global__ __launch_bounds__(1024) void k_cvec(
    const float* __restrict__ dWih, const float* __restrict__ dbih,
    const float* __restrict__ dbhh, const float* __restrict__ emT,
    float* __restrict__ cvecT)
{
  const int j = blockIdx.x * 16 + (threadIdx.x >> 6);
  const int b = threadIdx.x & 63;
  const float* wr = dWih + (size_t)j * 592 + 80;
  float a = dbih[j] + dbhh[j];
#pragma unroll 8
  for (int k = 0; k < 512; k++) a += wr[k] * emT[(size_t)k*64 + b];
  cvecT[(size_t)j*64 + b] = a;
}

// ============ decoder step: MFMA over K=1120, fused cell (one launch/step) ============
// 256 WGs x 256 thr (4 waves). WG wg owns units wg*4..+3; wave w = batch chunk w*16.
// Lane: unit = wg*4 + (l>>4), batch = w*16 + (l&15); acc[r] = gate r (i,f,g,o).
__global__ __launch_bounds__(256) void k_dec(
    const unsigned short* __restrict__ Adec, const unsigned short* __restrict__ hIn,
    const unsigned short* __restrict__ melLin, const float* __restrict__ cvecT,
    float* __restrict__ cT, unsigned short* __restrict__ hOut,
    unsigned short* __restrict__ HbufF, int t)
{
  const int tid = threadIdx.x, wg = blockIdx.x;
  const int l = tid & 63, w = tid >> 6;
  const int u = wg * 4 + (l >> 4);
  const int b = w * 16 + (l & 15);
  const int kq = (l >> 4) & 3;

  f32x4 acc;
  acc[0] = cvecT[(size_t)u * 64 + b];
  acc[1] = cvecT[(size_t)(1024 + u) * 64 + b];
  acc[2] = cvecT[(size_t)(2048 + u) * 64 + b];
  acc[3] = cvecT[(size_t)(3072 + u) * 64 + b];

  const short8* Ap = (const short8*)Adec + (size_t)wg * 35 * 64 + l;
  const short8* Hp = (const short8*)hIn + (size_t)b * 128 + kq;
  const short8* Mp = (const short8*)melLin + (size_t)(t * 64 + b) * 12 + kq;

#pragma unroll
  for (int ks = 0; ks < 32; ks++) {
    short8 a = Ap[ks * 64];
    short8 h = Hp[ks * 4];
    acc = __builtin_amdgcn_mfma_f32_16x16x32_bf16(a, h, acc, 0, 0, 0);
  }
#pragma unroll
  for (int ks = 32; ks < 35; ks++) {
    short8 a = Ap[ks * 64];
    short8 m = Mp[(ks - 32) * 4];
    acc = __builtin_amdgcn_mfma_f32_16x16x32_bf16(a, m, acc, 0, 0, 0);
  }

  float cOld = cT[(size_t)u * 64 + b];
  float c = sigf(acc[1]) * cOld + sigf(acc[0]) * tanhfast(acc[2]);
  float h = sigf(acc[3]) * tanhfast(c);
  cT[(size_t)u * 64 + b] = c;
  hOut[(size_t)b * 1024 + u] = f2bf(h);

  // Hbuf fragment-major write: m-row = t*64+b, k = u
  int m = t * 64 + b;
  int mt = m >> 4, mr = m & 15;
  int ksH = u >> 5, kg = (u >> 3) & 3, ii = u & 7;
  unsigned short hb = f2bf(h);
  HbufF[((size_t)(mt * 32 + ksH) * 512) + (mr + 16 * kg) * 8 + ii] = hb;
}

// ---------------- deferred decoder attention ----------------
__global__ __launch_bounds__(256) void k_attn(
    const float* __restrict__ Qd, const float* __restrict__ enc, float* __restrict__ attns)
{
  const int ch = blockIdx.x, bb = blockIdx.y;
  const int t0 = ch * 8;
  const int tid = threadIdx.x;
  __shared__ float Qt[8][516];
  __shared__ float sc[8][516];
  __shared__ float et[16][68];
  for (int i = tid; i < 8*512; i += 256) {
    int tr = i >> 9, k = i & 511;
    int tt = t0 + tr;
    Qt[tr][k] = (tt < TDEC) ? Qd[((size_t)tt*64 + bb)*512 + k] : 0.f;
  }
  const int tq = tid >> 5, sq = tid & 31;
  for (int st = 0; st < 8; st++) {
    int s0 = st * 64;
    float a0 = 0.f, a1 = 0.f;
    for (int kt = 0; kt < 512; kt += 16) {
      int sl = tid >> 2, k4 = (tid & 3) * 4;
      float4 ev = *(const float4*)(enc + ((size_t)bb*S + s0 + sl)*ENC + kt + k4);
      __syncthreads();
      et[k4+0][sl] = ev.x; et[k4+1][sl] = ev.y; et[k4+2][sl] = ev.z; et[k4+3][sl] = ev.w;
      __syncthreads();
#pragma unroll
      for (int kk = 0; kk < 16; kk++) {
        float q0 = Qt[tq][kt+kk];
        float2 e2 = *(const float2*)&et[kk][sq*2];
        a0 += q0*e2.x; a1 += q0*e2.y;
      }
    }
    *(float2*)&sc[tq][s0+sq*2] = make_float2(a0, a1);
  }
  __syncthreads();
  int row = tid >> 5, li = tid & 31;
  float m = -1e30f;
  for (int s = li; s < 512; s += 32) m = fmaxf(m, sc[row][s]);
#pragma unroll
  for (int off = 1; off < 32; off <<= 1) m = fmaxf(m, __shfl_xor(m, off, 64));
  float den = 0.f;
  for (int s = li; s < 512; s += 32) {
    float e = __expf(sc[row][s] - m);
    sc[row][s] = e;
    den += e;
  }
#pragma unroll
  for (int off = 1; off < 32; off <<= 1) den += __shfl_xor(den, off, 64);
  float inv = 1.f / den;
  int tt = t0 + row;
  if (tt < TDEC) {
    for (int s = li; s < 512; s += 32)
      attns[((size_t)bb*TDEC + tt)*512 + s] = sc[row][s] * inv;
  }
}

// ---------------- mel/stop epilogue (tmp stride 128) ----------------
__global__ void k_melout(const float* __restrict__ tmp,
                         float* __restrict__ mels, float* __restrict__ stops)
{
  int i = blockIdx.x * 256 + threadIdx.x;
  if (i >= 32000 * 128) return;
  int m = i >> 7, n = i & 127;
  int t = m >> 6, b = m & 63;
  float v = tmp[i];
  if (n < 80)       mels[((size_t)b*TDEC + t)*MEL + n] = v;
  else if (n == 80) stops[(size_t)b*TDEC + t] = sigf(v);
}

// ---------------- host launcher ----------------
extern "C" void kernel_launch(void* const* d_in, const int* in_sizes, int n_in,
                              void* d_out, int out_size, void* d_ws, size_t ws_size,
                              hipStream_t stream)
{
  (void)in_sizes; (void)n_in; (void)out_size;
  if (ws_size < WS_FLOATS * sizeof(float)) return;  // clean accuracy-fail diagnostic

  const int*   text       = (const int*)  d_in[0];
  const float* mel_target = (const float*)d_in[1];
  const float* emb_table  = (const float*)d_in[3];
  const float* Wih_f = (const float*)d_in[4];
  const float* Whh_f = (const float*)d_in[5];
  const float* bih_f = (const float*)d_in[6];
  const float* bhh_f = (const float*)d_in[7];
  const float* Wih_b = (const float*)d_in[8];
  const float* Whh_b = (const float*)d_in[9];
  const float* bih_b = (const float*)d_in[10];
  const float* bhh_b = (const float*)d_in[11];
  const float* tokens = (const float*)d_in[12];
  const float* q_w = (const float*)d_in[13];
  const float* q_b = (const float*)d_in[14];
  const float* k_w = (const float*)d_in[15];
  const float* k_b = (const float*)d_in[16];
  const float* proj_w = (const float*)d_in[17];
  const float* proj_b = (const float*)d_in[18];
  const float* dWih = (const float*)d_in[19];
  const float* dWhh = (const float*)d_in[20];
  const float* dbih = (const float*)d_in[21];
  const float* dbhh = (const float*)d_in[22];
  const float* attn_w = (const float*)d_in[23];
  const float* attn_b = (const float*)d_in[24];
  const float* mel_w = (const float*)d_in[25];
  const float* mel_b = (const float*)d_in[26];
  const float* stop_w = (const float*)d_in[27];
  const float* stop_b = (const float*)d_in[28];

  float* ws = (float*)d_ws;
  __half* preF = (__half*)(ws + OFF_P0);
  __half* preB = (__half*)(ws + OFF_P1);
  unsigned short* encFrag = (unsigned short*)(ws + OFF_P0);   // after scan
  unsigned short* HbufF   = (unsigned short*)(ws + OFF_P0);   // after qg
  float* qg = ws + OFF_P1;                                    // after scan
  float* Qd = ws + OFF_P1;                                    // after gst
  float* enc = ws + OFF_ENC;
  unsigned short* Aemb = (unsigned short*)(ws + OFF_ENC);     // before scan
  float* WhhT = ws + OFF_SCR;                                 // pre-scan only
  unsigned short* Adec   = (unsigned short*)(ws + OFF_SCR);   // post-scan
  unsigned short* melLin = (unsigned short*)(ws + OFF_SCR + SCR_MEL_SUB);
  float* tmpMS = ws + OFF_SCR;                                // after decoder
  unsigned short* WFF  = (unsigned short*)(ws + OFF_WFF);
  unsigned short* WFB  = (unsigned short*)(ws + OFF_WFB);
  unsigned short* QWF  = (unsigned short*)(ws + OFF_QWF);
  unsigned short* AWF  = (unsigned short*)(ws + OFF_AWF);
  unsigned short* WMSF = (unsigned short*)(ws + OFF_WMSF);
  float* bms   = ws + OFF_BMS;
  float* cvecT = ws + OFF_CVEC;
  float* cT    = ws + OFF_CT;
  unsigned short* hTb = (unsigned short*)(ws + OFF_HTB);      // 2 x 65536 bf16
  float* emT   = ws + OFF_EMT;
  float* kg    = ws + OFF_KG;
  float* swb   = ws + OFF_SW;
  float* style = ws + OFF_STYLE;

  float* out = (float*)d_out;
  float* out_mels  = out + MELS_OFF;
  float* out_attns = out + ATTNS_OFF;
  float* out_stops = out + STOPS_OFF;

  // ---- weight packing ----
  k_pack_bms<<<1, 128, 0, stream>>>(mel_b, stop_b, bms);
  k_pack_wms_frag<<<(8*32*64 + 255)/256, 256, 0, stream>>>(mel_w, stop_w, WMSF);
  k_pack_wfrag<<<(64*16*64 + 255)/256, 256, 0, stream>>>(Wih_f, WFF, 64, 16, 1024, 512);
  k_pack_wfrag<<<(64*16*64 + 255)/256, 256, 0, stream>>>(Wih_b, WFB, 64, 16, 1024, 512);
  k_pack_wfrag<<<(32*16*64 + 255)/256, 256, 0, stream>>>(q_w, QWF, 32, 16, 512, 512);
  k_pack_wfrag<<<(32*32*64 + 255)/256, 256, 0, stream>>>(attn_w, AWF, 32, 32, 512, 1024);
  k_transpose<<<dim3(32, 8, 2), 256, 0, stream>>>(Whh_f, Whh_b, WhhT);
  k_pack_aemb<<<(2048*16*64 + 255)/256, 256, 0, stream>>>(text, emb_table, Aemb);

  // GST keys (tiny fp32)
  k_gemm<<<dim3(8, 1), 256, 0, stream>>>(tokens, k_w, k_b, kg, 10, 512, 512);

  // ---- encoder input projections: bf16 MFMA, fp16 out ----
  k_mgemm<16,4,true><<<dim3(1024/256, 512), 256, 0, stream>>>(
      Aemb, WFF, bih_f, bhh_f, nullptr, preF, 1024);
  k_mgemm<16,4,true><<<dim3(1024/256, 512), 256, 0, stream>>>(
      Aemb, WFB, bih_b, bhh_b, nullptr, preB, 1024);

  // ---- encoder scan (consumes WhhT; SCR reused afterwards) ----
  k_enc_scan<<<64, 1024, 0, stream>>>(preF, preB, WhhT, enc);

  // ---- GST: q on pre-style enc, weights, style, enc update ----
  k_pack_enc<<<(2048*16*64 + 255)/256, 256, 0, stream>>>(enc, encFrag);
  k_mgemm<16,4,false><<<dim3(512/256, 512), 256, 0, stream>>>(
      encFrag, QWF, q_b, nullptr, qg, nullptr, 512);
  k_gst<<<64, 256, 0, stream>>>(qg, kg, swb);
  k_style<<<64, 256, 0, stream>>>(swb, tokens, proj_w, proj_b, style);
  k_encsm<<<64, 256, 0, stream>>>(enc, style, emT);

  // ---- decoder constants (SCR now free: WhhT dead) ----
  k_cvec<<<256, 1024, 0, stream>>>(dWih, dbih, dbhh, emT, cvecT);
  k_zero<<<(65536 + 255)/256, 256, 0, stream>>>(cT, 65536);
  k_zero<<<(65536 + 255)/256, 256, 0, stream>>>((float*)hTb, 65536);  // both h buffers
  k_pack_adec<<<(256*35*64 + 255)/256, 256, 0, stream>>>(dWhh, dWih, Adec);
  k_pack_mel<<<(32000*12 + 255)/256, 256, 0, stream>>>(mel_target, melLin);

  // ---- decoder scan: one MFMA kernel per step ----
  for (int t = 0; t < TDEC; t++) {
    const unsigned short* hIn = hTb + (t & 1) * 65536;
    unsigned short* hOut = hTb + ((t + 1) & 1) * 65536;
    k_dec<<<256, 256, 0, stream>>>(Adec, hIn, melLin, cvecT, cT, hOut, HbufF, t);
  }

  // ---- deferred outputs ----
  k_mgemm<32,4,false><<<dim3(512/256, 500), 256, 0, stream>>>(
      HbufF, AWF, attn_b, nullptr, Qd, nullptr, 512);
  k_mgemm<32,2,false><<<dim3(1, 500), 256, 0, stream>>>(
      HbufF, WMSF, bms, nullptr, tmpMS, nullptr, 128);
  k_attn<<<dim3(63, 64), 256, 0, stream>>>(Qd, enc, out_attns);
  k_melout<<<(32000*128 + 255)/256, 256, 0, stream>>>(tmpMS, out_mels, out_stops);
}